// Round 6
// baseline (162.410 us; speedup 1.0000x reference)
//
#include <hip/hip_runtime.h>

typedef __bf16 bf16_t;
typedef __bf16 bf16x8 __attribute__((ext_vector_type(8)));
typedef __bf16 bf16x4 __attribute__((ext_vector_type(4)));
typedef float f32x4 __attribute__((ext_vector_type(4)));
typedef float f32x16 __attribute__((ext_vector_type(16)));

#define M_DIM 4096
#define N_DIM 4096   // 2 * OUT_FEATURES
#define K_DIM 4096   // 2 * IN_FEATURES
#define OUTF 2048
#define INF 2048
#define LDK 4096
#define NT 64        // K-tiles of 64

// ---------------------------------------------------------------------------
// Pack kernel: build bf16 A = [x_re | x_im]  (4096 x 4096)
//              and  bf16 B = [[w_re, -w_im]; [w_im, w_re]] (4096 x 4096)
// ---------------------------------------------------------------------------
__global__ __launch_bounds__(256) void pack_ab(
    const float* __restrict__ xre, const float* __restrict__ xim,
    const float* __restrict__ wre, const float* __restrict__ wim,
    bf16_t* __restrict__ Abf, bf16_t* __restrict__ Bbf)
{
  size_t gid = (size_t)blockIdx.x * 256 + threadIdx.x;
  size_t e8  = gid * 8;
  const size_t MAT = (size_t)4096 * 4096;
  bool isB = e8 >= MAT;
  size_t e = isB ? (e8 - MAT) : e8;
  int row = (int)(e >> 12);
  int k   = (int)(e & 4095);

  const float* src;
  float s = 1.0f;
  if (!isB) {
    src = (k < INF) ? (xre + (size_t)row * INF + k)
                    : (xim + (size_t)row * INF + (k - INF));
  } else {
    if (row < OUTF) {
      if (k < INF) { src = wre + (size_t)row * INF + k; }
      else         { src = wim + (size_t)row * INF + (k - INF); s = -1.0f; }
    } else {
      int o = row - OUTF;
      src = (k < INF) ? (wim + (size_t)o * INF + k)
                      : (wre + (size_t)o * INF + (k - INF));
    }
  }
  const float4* p = reinterpret_cast<const float4*>(src);
  float4 f0 = p[0];
  float4 f1 = p[1];
  bf16x8 v;
  v[0] = (bf16_t)(f0.x * s); v[1] = (bf16_t)(f0.y * s);
  v[2] = (bf16_t)(f0.z * s); v[3] = (bf16_t)(f0.w * s);
  v[4] = (bf16_t)(f1.x * s); v[5] = (bf16_t)(f1.y * s);
  v[6] = (bf16_t)(f1.z * s); v[7] = (bf16_t)(f1.w * s);
  bf16_t* dst = (isB ? Bbf : Abf) + e;
  *reinterpret_cast<bf16x8*>(dst) = v;
}

// ---------------------------------------------------------------------------
__device__ __forceinline__ void gld_lds16(const void* g, void* l) {
  __builtin_amdgcn_global_load_lds(
      (const __attribute__((address_space(1))) void*)g,
      (__attribute__((address_space(3))) void*)l,
      16, 0, 0);
}

// ---------------------------------------------------------------------------
// 256x256 GEMM, R3-proven schedule + 32x32x16 MFMA (R6).
//   8 waves = 512 thr (2M x 4N), per-wave 128x64 out (4x2 tiles of 32x32),
//   BK=64 (4 k-steps of 16), LDS 128 KiB dbuf.
//   Swizzle (R3-verified, conflicts==0; mask depends only on lane&7 so it
//   carries over to 32-row fragments):
//     phys_kbyte = logical_kbyte ^ ((row&3)<<4) ^ (((row>>2)&1)<<6)
//   Phases: P1 (qm0,qn0) / P2 (qm0,qn1) / P3 (qm1,qn1) / P4 (qm1,qn0),
//   staging t+1 A1|B0|B1 at P1|P2|P3 and t+2 A0 at P4 with vmcnt(2).
// ---------------------------------------------------------------------------
__global__ __launch_bounds__(512, 2) void gemm256(
    const bf16_t* __restrict__ A, const bf16_t* __restrict__ B,
    float* __restrict__ out)
{
  // LDS: buf c at c*65536 B; within buf: A-half0|A-half1|B-half0|B-half1,
  // each half = 128 rows x 64 cols bf16 = 16384 B (row stride 128 B).
  __shared__ alignas(16) bf16_t lds[2 * 32768];
  char* Lb = (char*)lds;

  const int tid  = threadIdx.x;
  const int lane = tid & 63;
  const int wid  = tid >> 6;
  const int wm   = wid >> 2;   // 0..1  -> rows wm*128..+127  (A-half wm)
  const int wn   = wid & 3;    // 0..3  -> cols wn*64..+63
  const int l31  = lane & 31;
  const int hi   = lane >> 5;                                 // k-slot bit
  const int kg2  = hi * 16;                                   // logical kbyte
  const int xm   = ((lane & 3) << 4) | (((lane >> 2) & 1) << 6); // row-XOR

  int bid = blockIdx.x;
  int swz = (bid & 7) * 32 + (bid >> 3);   // XCD-aware, 256 blocks % 8 == 0
  const int bm = swz >> 4;                  // 0..15
  const int bn = swz & 15;                  // 0..15

  // Staging source precompute: physical P = j*8192 + tid*16 within a half;
  // row = P>>7, p = P&127; logical kbyte = p ^ ((row&3)<<4) ^ ((row>>2&1)<<6)
  int rS[2], kS[2];
#pragma unroll
  for (int j = 0; j < 2; ++j) {
    int P   = j * 8192 + tid * 16;
    int row = P >> 7;
    int p   = P & 127;
    int L   = p ^ ((row & 3) << 4) ^ (((row >> 2) & 1) << 6);
    rS[j] = row;
    kS[j] = L >> 1;           // k element (0..63)
  }
  const bf16_t* As0 = A + (size_t)(bm * 256 + rS[0]) * LDK + kS[0];
  const bf16_t* As1 = A + (size_t)(bm * 256 + rS[1]) * LDK + kS[1];
  const bf16_t* Bs0 = B + (size_t)(bn * 256 + rS[0]) * LDK + kS[0];
  const bf16_t* Bs1 = B + (size_t)(bn * 256 + rS[1]) * LDK + kS[1];
  const int dst16 = tid * 16;

#define STAGE_A(t, h, c) do {                                                  \
    gld_lds16(As0 + (size_t)(h) * 128 * LDK + (t) * 64,                        \
              Lb + (c) * 65536 + (h) * 16384 + dst16);                         \
    gld_lds16(As1 + (size_t)(h) * 128 * LDK + (t) * 64,                        \
              Lb + (c) * 65536 + (h) * 16384 + 8192 + dst16);                  \
  } while (0)
#define STAGE_B(t, h, c) do {                                                  \
    gld_lds16(Bs0 + (size_t)(h) * 128 * LDK + (t) * 64,                        \
              Lb + (c) * 65536 + 32768 + (h) * 16384 + dst16);                 \
    gld_lds16(Bs1 + (size_t)(h) * 128 * LDK + (t) * 64,                        \
              Lb + (c) * 65536 + 32768 + (h) * 16384 + 8192 + dst16);          \
  } while (0)
// A frag (32x32x16): M-tile Mt (0..3), k-step ks (0..3).
// row-in-half = Mt*32 + l31 (half = wm); logical kbyte = ks*32 + kg2.
#define RD_A32(c, Mt, ks)                                                      \
  (*(const bf16x8*)(Lb + (c) * 65536 + wm * 16384 +                            \
                    ((Mt) * 32 + l31) * 128 + ((((ks) * 32) | kg2) ^ xm)))
// B frag: N-tile Nt (0..1). nlocal = wn*64 + Nt*32 -> half nlocal>>7,
// row-in-half = (nlocal&127) + l31.
#define RD_B32(c, Nt, ks)                                                      \
  (*(const bf16x8*)(Lb + (c) * 65536 + 32768 +                                 \
                    (((wn * 64 + (Nt) * 32) >> 7) * 16384) +                   \
                    (((wn * 64 + (Nt) * 32) & 127) + l31) * 128 +              \
                    ((((ks) * 32) | kg2) ^ xm)))
#define BAR()    __builtin_amdgcn_s_barrier()
#define LGKM0()  asm volatile("s_waitcnt lgkmcnt(0)" ::: "memory")
#define MFMA32(a, b, c) __builtin_amdgcn_mfma_f32_32x32x16_bf16((a), (b), (c), 0, 0, 0)

  f32x16 acc[4][2];
#pragma unroll
  for (int i = 0; i < 4; ++i)
#pragma unroll
    for (int j = 0; j < 2; ++j)
      acc[i][j] = (f32x16){0.f};

  // Prologue: tile0 fully into buf0; tile1's A-half0 into buf1 (1 HT in flight)
  STAGE_A(0, 0, 0); STAGE_A(0, 1, 0);
  STAGE_B(0, 0, 0); STAGE_B(0, 1, 0);
  STAGE_A(1, 0, 1);
  asm volatile("s_waitcnt vmcnt(2)" ::: "memory");
  BAR();

  for (int t = 0; t < NT; ++t) {
    const int c = t & 1;
    bf16x8 a0[2][4], a1[2][4], b0[4], b1[4];

    // ---- P1: quadrant (qm0, qn0). reads: A Mt0,1 (8), B Nt0 (4). stage A1.
#pragma unroll
    for (int m = 0; m < 2; ++m)
#pragma unroll
      for (int ks = 0; ks < 4; ++ks)
        a0[m][ks] = RD_A32(c, m, ks);
#pragma unroll
    for (int ks = 0; ks < 4; ++ks)
      b0[ks] = RD_B32(c, 0, ks);
    if (t + 1 < NT) STAGE_A(t + 1, 1, c ^ 1);
    BAR(); LGKM0();
    __builtin_amdgcn_s_setprio(1);
#pragma unroll
    for (int ks = 0; ks < 4; ++ks)
#pragma unroll
      for (int m = 0; m < 2; ++m)
        acc[m][0] = MFMA32(a0[m][ks], b0[ks], acc[m][0]);
    __builtin_amdgcn_s_setprio(0);
    BAR();

    // ---- P2: quadrant (qm0, qn1). reads: B Nt1 (4). stage B0.
#pragma unroll
    for (int ks = 0; ks < 4; ++ks)
      b1[ks] = RD_B32(c, 1, ks);
    if (t + 1 < NT) STAGE_B(t + 1, 0, c ^ 1);
    BAR(); LGKM0();
    __builtin_amdgcn_s_setprio(1);
#pragma unroll
    for (int ks = 0; ks < 4; ++ks)
#pragma unroll
      for (int m = 0; m < 2; ++m)
        acc[m][1] = MFMA32(a0[m][ks], b1[ks], acc[m][1]);
    __builtin_amdgcn_s_setprio(0);
    BAR();

    // ---- P3: quadrant (qm1, qn1). reads: A Mt2,3 (8). stage B1.
#pragma unroll
    for (int m = 0; m < 2; ++m)
#pragma unroll
      for (int ks = 0; ks < 4; ++ks)
        a1[m][ks] = RD_A32(c, 2 + m, ks);
    if (t + 1 < NT) STAGE_B(t + 1, 1, c ^ 1);
    BAR(); LGKM0();
    __builtin_amdgcn_s_setprio(1);
#pragma unroll
    for (int ks = 0; ks < 4; ++ks)
#pragma unroll
      for (int m = 0; m < 2; ++m)
        acc[2 + m][1] = MFMA32(a1[m][ks], b1[ks], acc[2 + m][1]);
    __builtin_amdgcn_s_setprio(0);
    BAR();

    // ---- P4: quadrant (qm1, qn0). no reads. stage t+2 A0 into buf c (safe:
    // all reads of buf c completed by P3's lgkmcnt+barrier). counted vmcnt.
    if (t + 2 < NT) STAGE_A(t + 2, 0, c);
    __builtin_amdgcn_s_setprio(1);
#pragma unroll
    for (int ks = 0; ks < 4; ++ks)
#pragma unroll
      for (int m = 0; m < 2; ++m)
        acc[2 + m][0] = MFMA32(a1[m][ks], b0[ks], acc[2 + m][0]);
    __builtin_amdgcn_s_setprio(0);
    if (t + 2 < NT) {
      asm volatile("s_waitcnt vmcnt(2)" ::: "memory");
    } else if (t + 1 < NT) {
      asm volatile("s_waitcnt vmcnt(0)" ::: "memory");
    }
    BAR();
  }

  // Epilogue: 32x32 C/D layout col=lane&31, row=(reg&3)+8*(reg>>2)+4*(lane>>5)
  // (verified m74/m101).
  const size_t imOff = (size_t)M_DIM * OUTF;
  const bool isIm = (bn * 256) >= OUTF;          // bn>=8 -> imaginary half
  float* obase = out + (isIm ? imOff : 0);
  const int colBase = bn * 256 - (isIm ? OUTF : 0) + wn * 64;
#pragma unroll
  for (int Mt = 0; Mt < 4; ++Mt) {
#pragma unroll
    for (int Nt = 0; Nt < 2; ++Nt) {
      f32x16 v = acc[Mt][Nt];
      int gc = colBase + Nt * 32 + l31;
      int grb = bm * 256 + wm * 128 + Mt * 32 + 4 * hi;
#pragma unroll
      for (int reg = 0; reg < 16; ++reg) {
        int gr = grb + (reg & 3) + 8 * (reg >> 2);
        obase[(size_t)gr * OUTF + gc] = v[reg];
      }
    }
  }
#undef STAGE_A
#undef STAGE_B
#undef RD_A32
#undef RD_B32
#undef BAR
#undef LGKM0
#undef MFMA32
}

// ---------------------------------------------------------------------------
// Fallback: fused fp32->bf16 conversion + GEMM (no workspace needed).
// ---------------------------------------------------------------------------
__global__ __launch_bounds__(256) void gemm_fused(
    const float* __restrict__ xre, const float* __restrict__ xim,
    const float* __restrict__ wre, const float* __restrict__ wim,
    float* __restrict__ out)
{
  __shared__ alignas(16) bf16_t As[128 * 40];
  __shared__ alignas(16) bf16_t Bs[128 * 40];

  int tid = threadIdx.x;
  int bid = blockIdx.x;
  int swz = (bid & 7) * 128 + (bid >> 3);
  int bm = swz >> 5;
  int bn = swz & 31;

  int lane = tid & 63;
  int w    = tid >> 6;
  int wm   = (w >> 1) * 64;
  int wn   = (w & 1) * 64;
  int lr   = lane & 15;
  int lk   = (lane >> 4) * 8;

  f32x4 acc[4][4];
#pragma unroll
  for (int m = 0; m < 4; ++m)
#pragma unroll
    for (int n = 0; n < 4; ++n)
      acc[m][n] = (f32x4){0.f, 0.f, 0.f, 0.f};

  int srow = tid >> 3;
  int scol = (tid & 7) * 4;

  bool nIm  = (bn * 128) >= OUTF;
  int nbase = nIm ? (bn * 128 - OUTF) : (bn * 128);

  for (int kt = 0; kt < K_DIM / 32; ++kt) {
    int k0 = kt * 32;
    bool kHi = (k0 >= INF);
    int kk = kHi ? (k0 - INF) : k0;

    const float* Asrc = (kHi ? xim : xre) + (size_t)(bm * 128) * INF + kk;
    const float* Bsrc;
    float s = 1.0f;
    if (!nIm) { if (!kHi) { Bsrc = wre; } else { Bsrc = wim; s = -1.0f; } }
    else      { Bsrc = kHi ? wre : wim; }
    Bsrc += (size_t)nbase * INF + kk;

    float4 av[4], bv[4];
#pragma unroll
    for (int i = 0; i < 4; ++i) {
      av[i] = *reinterpret_cast<const float4*>(Asrc + (size_t)(srow + i * 32) * INF + scol);
      bv[i] = *reinterpret_cast<const float4*>(Bsrc + (size_t)(srow + i * 32) * INF + scol);
    }
    __syncthreads();
#pragma unroll
    for (int i = 0; i < 4; ++i) {
      bf16x4 a4, b4;
      a4[0] = (bf16_t)av[i].x; a4[1] = (bf16_t)av[i].y;
      a4[2] = (bf16_t)av[i].z; a4[3] = (bf16_t)av[i].w;
      b4[0] = (bf16_t)(bv[i].x * s); b4[1] = (bf16_t)(bv[i].y * s);
      b4[2] = (bf16_t)(bv[i].z * s); b4[3] = (bf16_t)(bv[i].w * s);
      *reinterpret_cast<bf16x4*>(&As[(srow + i * 32) * 40 + scol]) = a4;
      *reinterpret_cast<bf16x4*>(&Bs[(srow + i * 32) * 40 + scol]) = b4;
    }
    __syncthreads();

    bf16x8 a[4], b[4];
#pragma unroll
    for (int m = 0; m < 4; ++m)
      a[m] = *reinterpret_cast<const bf16x8*>(&As[(wm + m * 16 + lr) * 40 + lk]);
#pragma unroll
    for (int n = 0; n < 4; ++n)
      b[n] = *reinterpret_cast<const bf16x8*>(&Bs[(wn + n * 16 + lr) * 40 + lk]);
#pragma unroll
    for (int m = 0; m < 4; ++m)
#pragma unroll
      for (int n = 0; n < 4; ++n)
        acc[m][n] = __builtin_amdgcn_mfma_f32_16x16x32_bf16(a[m], b[n], acc[m][n], 0, 0, 0);
  }
  __syncthreads();

  const size_t imOff = (size_t)M_DIM * OUTF;
  int fq = (lane >> 4) * 4;
#pragma unroll
  for (int m = 0; m < 4; ++m) {
    int gr = bm * 128 + wm + m * 16 + fq;
#pragma unroll
    for (int n = 0; n < 4; ++n) {
      int gc = bn * 128 + wn + n * 16 + lr;
      float* dst = (gc < OUTF) ? (out + (size_t)gr * OUTF + gc)
                               : (out + imOff + (size_t)gr * OUTF + (gc - OUTF));
#pragma unroll
      for (int j = 0; j < 4; ++j)
        dst[(size_t)j * OUTF] = acc[m][n][j];
    }
  }
}

// ---------------------------------------------------------------------------
extern "C" void kernel_launch(void* const* d_in, const int* in_sizes, int n_in,
                              void* d_out, int out_size, void* d_ws, size_t ws_size,
                              hipStream_t stream) {
  const float* xre = (const float*)d_in[0];
  const float* xim = (const float*)d_in[1];
  const float* wre = (const float*)d_in[2];
  const float* wim = (const float*)d_in[3];
  float* out = (float*)d_out;

  const size_t need = (size_t)2 * 4096 * 4096 * sizeof(bf16_t);  // 64 MiB
  if (ws_size >= need) {
    bf16_t* Abf = (bf16_t*)d_ws;
    bf16_t* Bbf = Abf + (size_t)4096 * 4096;
    hipLaunchKernelGGL(pack_ab, dim3(16384), dim3(256), 0, stream,
                       xre, xim, wre, wim, Abf, Bbf);
    hipLaunchKernelGGL(gemm256, dim3(256), dim3(512), 0, stream,
                       Abf, Bbf, out);
  } else {
    hipLaunchKernelGGL(gemm_fused, dim3(1024), dim3(256), 0, stream,
                       xre, xim, wre, wim, out);
  }
}

// Round 7
// 145.629 us; speedup vs baseline: 1.1152x; 1.1152x over previous
//
#include <hip/hip_runtime.h>

typedef __bf16 bf16_t;
typedef __bf16 bf16x8 __attribute__((ext_vector_type(8)));
typedef __bf16 bf16x4 __attribute__((ext_vector_type(4)));
typedef float f32x4 __attribute__((ext_vector_type(4)));

#define M_DIM 4096
#define N_DIM 4096   // 2 * OUT_FEATURES
#define K_DIM 4096   // 2 * IN_FEATURES
#define OUTF 2048
#define INF 2048
#define LDK 4096
#define NT 64        // K-tiles of 64

// ---------------------------------------------------------------------------
// Pack kernel: build bf16 A = [x_re | x_im]  (4096 x 4096)
//              and  bf16 B = [[w_re, -w_im]; [w_im, w_re]] (4096 x 4096)
// ---------------------------------------------------------------------------
__global__ __launch_bounds__(256) void pack_ab(
    const float* __restrict__ xre, const float* __restrict__ xim,
    const float* __restrict__ wre, const float* __restrict__ wim,
    bf16_t* __restrict__ Abf, bf16_t* __restrict__ Bbf)
{
  size_t gid = (size_t)blockIdx.x * 256 + threadIdx.x;
  size_t e8  = gid * 8;
  const size_t MAT = (size_t)4096 * 4096;
  bool isB = e8 >= MAT;
  size_t e = isB ? (e8 - MAT) : e8;
  int row = (int)(e >> 12);
  int k   = (int)(e & 4095);

  const float* src;
  float s = 1.0f;
  if (!isB) {
    src = (k < INF) ? (xre + (size_t)row * INF + k)
                    : (xim + (size_t)row * INF + (k - INF));
  } else {
    if (row < OUTF) {
      if (k < INF) { src = wre + (size_t)row * INF + k; }
      else         { src = wim + (size_t)row * INF + (k - INF); s = -1.0f; }
    } else {
      int o = row - OUTF;
      src = (k < INF) ? (wim + (size_t)o * INF + k)
                      : (wre + (size_t)o * INF + (k - INF));
    }
  }
  const float4* p = reinterpret_cast<const float4*>(src);
  float4 f0 = p[0];
  float4 f1 = p[1];
  bf16x8 v;
  v[0] = (bf16_t)(f0.x * s); v[1] = (bf16_t)(f0.y * s);
  v[2] = (bf16_t)(f0.z * s); v[3] = (bf16_t)(f0.w * s);
  v[4] = (bf16_t)(f1.x * s); v[5] = (bf16_t)(f1.y * s);
  v[6] = (bf16_t)(f1.z * s); v[7] = (bf16_t)(f1.w * s);
  bf16_t* dst = (isB ? Bbf : Abf) + e;
  *reinterpret_cast<bf16x8*>(dst) = v;
}

// ---------------------------------------------------------------------------
__device__ __forceinline__ void gld_lds16(const void* g, void* l) {
  __builtin_amdgcn_global_load_lds(
      (const __attribute__((address_space(1))) void*)g,
      (__attribute__((address_space(3))) void*)l,
      16, 0, 0);
}

// ---------------------------------------------------------------------------
// 256x256 GEMM, read-ahead-1 quadrant schedule (R7).
//   8 waves = 512 thr (2M x 4N), per-wave 128x64 out, BK=64, 128 KiB dbuf.
//   16x16x32 MFMA (R6's 32x32 regressed: conflicts).
//   Swizzle (R3-verified, conflicts==0):
//     phys_kbyte = logical_kbyte ^ ((row&3)<<4) ^ (((row>>2)&1)<<6)
//   Quadrant order Q1(0,0) Q2(0,1) Q3(1,1) Q4(1,0); each phase issues the
//   NEXT quadrant's ds_reads, then a counted lgkm covers only the current
//   quadrant (FIFO) -> next reads drain UNDER current MFMA. One barrier per
//   phase (region-safety re-derived: every staged region's readers complete
//   at a counted lgkm before an intervening barrier). vmcnt(2) boundary.
// ---------------------------------------------------------------------------

template<int QM, int QN>
__device__ __forceinline__ void mfma_quad(f32x4 (&acc)[8][4],
                                          const bf16x8 (&aF)[4][2],
                                          const bf16x8 (&bF)[2][2]) {
  __builtin_amdgcn_s_setprio(1);
#pragma unroll
  for (int m = 0; m < 4; ++m)
#pragma unroll
    for (int n = 0; n < 2; ++n) {
      f32x4 v = acc[QM * 4 + m][QN * 2 + n];
      v = __builtin_amdgcn_mfma_f32_16x16x32_bf16(aF[m][0], bF[n][0], v, 0, 0, 0);
      v = __builtin_amdgcn_mfma_f32_16x16x32_bf16(aF[m][1], bF[n][1], v, 0, 0, 0);
      acc[QM * 4 + m][QN * 2 + n] = v;
    }
  __builtin_amdgcn_s_setprio(0);
}

__global__ __launch_bounds__(512, 2) void gemm256(
    const bf16_t* __restrict__ A, const bf16_t* __restrict__ B,
    float* __restrict__ out)
{
  // LDS: buf c at c*65536 B; within buf: A-half0|A-half1|B-half0|B-half1,
  // each half = 128 rows x 64 cols bf16 = 16384 B (row stride 128 B).
  __shared__ alignas(16) bf16_t lds[2 * 32768];
  char* Lb = (char*)lds;

  const int tid  = threadIdx.x;
  const int lane = tid & 63;
  const int wid  = tid >> 6;
  const int wm   = wid >> 2;   // 0..1  -> rows wm*128..+127  (A-half wm)
  const int wn   = wid & 3;    // 0..3  -> cols wn*64..+63
  const int lr   = lane & 15;
  const int kg   = (lane >> 4) * 16;                         // logical slot
  const int xm   = ((lr & 3) << 4) | (((lr >> 2) & 1) << 6); // row-XOR mask

  int bid = blockIdx.x;
  int swz = (bid & 7) * 32 + (bid >> 3);   // XCD-aware, 256 blocks % 8 == 0
  const int bm = swz >> 4;                  // 0..15
  const int bn = swz & 15;                  // 0..15

  // Staging source precompute: physical P = j*8192 + tid*16 within a half;
  // row = P>>7, p = P&127; logical kbyte = p ^ ((row&3)<<4) ^ ((row>>2&1)<<6)
  int rS[2], kS[2];
#pragma unroll
  for (int j = 0; j < 2; ++j) {
    int P   = j * 8192 + tid * 16;
    int row = P >> 7;
    int p   = P & 127;
    int L   = p ^ ((row & 3) << 4) ^ (((row >> 2) & 1) << 6);
    rS[j] = row;
    kS[j] = L >> 1;           // k element (0..63)
  }
  const bf16_t* As0 = A + (size_t)(bm * 256 + rS[0]) * LDK + kS[0];
  const bf16_t* As1 = A + (size_t)(bm * 256 + rS[1]) * LDK + kS[1];
  const bf16_t* Bs0 = B + (size_t)(bn * 256 + rS[0]) * LDK + kS[0];
  const bf16_t* Bs1 = B + (size_t)(bn * 256 + rS[1]) * LDK + kS[1];
  const int dst16 = tid * 16;

#define STAGE_A(t, h, c) do {                                                  \
    gld_lds16(As0 + (size_t)(h) * 128 * LDK + (t) * 64,                        \
              Lb + (c) * 65536 + (h) * 16384 + dst16);                         \
    gld_lds16(As1 + (size_t)(h) * 128 * LDK + (t) * 64,                        \
              Lb + (c) * 65536 + (h) * 16384 + 8192 + dst16);                  \
  } while (0)
#define STAGE_B(t, h, c) do {                                                  \
    gld_lds16(Bs0 + (size_t)(h) * 128 * LDK + (t) * 64,                        \
              Lb + (c) * 65536 + 32768 + (h) * 16384 + dst16);                 \
    gld_lds16(Bs1 + (size_t)(h) * 128 * LDK + (t) * 64,                        \
              Lb + (c) * 65536 + 32768 + (h) * 16384 + 8192 + dst16);          \
  } while (0)
// A frag: row-in-half = qm*64+m*16+lr (half = wm); swizzled kbyte
#define RD_A(c, qm, m, ks)                                                     \
  (*(const bf16x8*)(Lb + (c) * 65536 + wm * 16384 +                            \
                    ((qm) * 64 + (m) * 16 + lr) * 128 +                        \
                    ((((ks) * 64) | kg) ^ xm)))
// B frag: row = wn*64+qn*32+n*16+lr -> half wn>>1, row-in-half rest
#define RD_B(c, qn, n, ks)                                                     \
  (*(const bf16x8*)(Lb + (c) * 65536 + 32768 + (wn >> 1) * 16384 +             \
                    ((wn & 1) * 64 + (qn) * 32 + (n) * 16 + lr) * 128 +        \
                    ((((ks) * 64) | kg) ^ xm)))
#define BAR()   __builtin_amdgcn_s_barrier()
#define SB()    __builtin_amdgcn_sched_barrier(0)

  f32x4 acc[8][4];
#pragma unroll
  for (int i = 0; i < 8; ++i)
#pragma unroll
    for (int j = 0; j < 4; ++j)
      acc[i][j] = (f32x4){0.f, 0.f, 0.f, 0.f};

  // Prologue: tile0 fully into buf0; tile1's A-half0 into buf1 (1 HT in flight)
  STAGE_A(0, 0, 0); STAGE_A(0, 1, 0);
  STAGE_B(0, 0, 0); STAGE_B(0, 1, 0);
  STAGE_A(1, 0, 1);
  asm volatile("s_waitcnt vmcnt(2)" ::: "memory");
  BAR();

  for (int t = 0; t < NT; ++t) {
    const int c = t & 1;
    bf16x8 a0[4][2], a1[4][2], b0[2][2], b1[2][2];

    // ---- P1: issue Q1 reads (a0:8, b0:4), then Q2 reads (b1:4, read-ahead).
    // lgkm(4) -> Q1 done (FIFO; Q2's 4 still draining under Q1 MFMA).
#pragma unroll
    for (int m = 0; m < 4; ++m) {
      a0[m][0] = RD_A(c, 0, m, 0);
      a0[m][1] = RD_A(c, 0, m, 1);
    }
#pragma unroll
    for (int n = 0; n < 2; ++n) {
      b0[n][0] = RD_B(c, 0, n, 0);
      b0[n][1] = RD_B(c, 0, n, 1);
    }
    SB();
#pragma unroll
    for (int n = 0; n < 2; ++n) {
      b1[n][0] = RD_B(c, 1, n, 0);
      b1[n][1] = RD_B(c, 1, n, 1);
    }
    SB();
    if (t + 1 < NT) STAGE_A(t + 1, 1, c ^ 1);   // A1-c^1 readers done t-1 P3
    asm volatile("s_waitcnt lgkmcnt(4)" ::: "memory");
    SB();
    mfma_quad<0, 0>(acc, a0, b0);
    BAR();

    // ---- P2: issue Q3 reads (a1:8). lgkm(8) -> Q2 done; Q3 drains under Q2.
#pragma unroll
    for (int m = 0; m < 4; ++m) {
      a1[m][0] = RD_A(c, 1, m, 0);
      a1[m][1] = RD_A(c, 1, m, 1);
    }
    SB();
    if (t + 1 < NT) STAGE_B(t + 1, 0, c ^ 1);   // b0-c^1 readers done t-1 P1
    asm volatile("s_waitcnt lgkmcnt(8)" ::: "memory");
    SB();
    mfma_quad<0, 1>(acc, a0, b1);
    BAR();

    // ---- P3: no new reads. lgkm(0) -> Q3 done.
    if (t + 1 < NT) STAGE_B(t + 1, 1, c ^ 1);   // b1-c^1 readers done t-1 P2
    asm volatile("s_waitcnt lgkmcnt(0)" ::: "memory");
    SB();
    mfma_quad<1, 1>(acc, a1, b1);
    BAR();

    // ---- P4: no reads. stage t+2 A0 into buf c (a0-c readers done at t P1's
    // lgkm(4), barrier P1-end intervenes). counted vmcnt boundary.
    if (t + 2 < NT) STAGE_A(t + 2, 0, c);
    mfma_quad<1, 0>(acc, a1, b0);
    if (t + 2 < NT) {
      asm volatile("s_waitcnt vmcnt(2)" ::: "memory");
    } else if (t + 1 < NT) {
      asm volatile("s_waitcnt vmcnt(0)" ::: "memory");
    }
    BAR();
  }

  // Epilogue: C/D layout col=lane&15, row=(lane>>4)*4+j (verified m89/m91)
  const size_t imOff = (size_t)M_DIM * OUTF;
  const int fq = (lane >> 4) * 4;
  const bool isIm = (bn * 256) >= OUTF;          // bn>=8 -> imaginary half
  float* obase = out + (isIm ? imOff : 0);
  const int colBase = bn * 256 - (isIm ? OUTF : 0) + wn * 64;
#pragma unroll
  for (int ar = 0; ar < 8; ++ar) {
    int gr = bm * 256 + wm * 128 + ar * 16 + fq;
#pragma unroll
    for (int cc = 0; cc < 4; ++cc) {
      int gc = colBase + cc * 16 + lr;
#pragma unroll
      for (int j = 0; j < 4; ++j)
        obase[(size_t)(gr + j) * OUTF + gc] = acc[ar][cc][j];
    }
  }
#undef STAGE_A
#undef STAGE_B
#undef RD_A
#undef RD_B
#undef BAR
#undef SB
}

// ---------------------------------------------------------------------------
// Fallback: fused fp32->bf16 conversion + GEMM (no workspace needed).
// ---------------------------------------------------------------------------
__global__ __launch_bounds__(256) void gemm_fused(
    const float* __restrict__ xre, const float* __restrict__ xim,
    const float* __restrict__ wre, const float* __restrict__ wim,
    float* __restrict__ out)
{
  __shared__ alignas(16) bf16_t As[128 * 40];
  __shared__ alignas(16) bf16_t Bs[128 * 40];

  int tid = threadIdx.x;
  int bid = blockIdx.x;
  int swz = (bid & 7) * 128 + (bid >> 3);
  int bm = swz >> 5;
  int bn = swz & 31;

  int lane = tid & 63;
  int w    = tid >> 6;
  int wm   = (w >> 1) * 64;
  int wn   = (w & 1) * 64;
  int lr   = lane & 15;
  int lk   = (lane >> 4) * 8;

  f32x4 acc[4][4];
#pragma unroll
  for (int m = 0; m < 4; ++m)
#pragma unroll
    for (int n = 0; n < 4; ++n)
      acc[m][n] = (f32x4){0.f, 0.f, 0.f, 0.f};

  int srow = tid >> 3;
  int scol = (tid & 7) * 4;

  bool nIm  = (bn * 128) >= OUTF;
  int nbase = nIm ? (bn * 128 - OUTF) : (bn * 128);

  for (int kt = 0; kt < K_DIM / 32; ++kt) {
    int k0 = kt * 32;
    bool kHi = (k0 >= INF);
    int kk = kHi ? (k0 - INF) : k0;

    const float* Asrc = (kHi ? xim : xre) + (size_t)(bm * 128) * INF + kk;
    const float* Bsrc;
    float s = 1.0f;
    if (!nIm) { if (!kHi) { Bsrc = wre; } else { Bsrc = wim; s = -1.0f; } }
    else      { Bsrc = kHi ? wre : wim; }
    Bsrc += (size_t)nbase * INF + kk;

    float4 av[4], bv[4];
#pragma unroll
    for (int i = 0; i < 4; ++i) {
      av[i] = *reinterpret_cast<const float4*>(Asrc + (size_t)(srow + i * 32) * INF + scol);
      bv[i] = *reinterpret_cast<const float4*>(Bsrc + (size_t)(srow + i * 32) * INF + scol);
    }
    __syncthreads();
#pragma unroll
    for (int i = 0; i < 4; ++i) {
      bf16x4 a4, b4;
      a4[0] = (bf16_t)av[i].x; a4[1] = (bf16_t)av[i].y;
      a4[2] = (bf16_t)av[i].z; a4[3] = (bf16_t)av[i].w;
      b4[0] = (bf16_t)(bv[i].x * s); b4[1] = (bf16_t)(bv[i].y * s);
      b4[2] = (bf16_t)(bv[i].z * s); b4[3] = (bf16_t)(bv[i].w * s);
      *reinterpret_cast<bf16x4*>(&As[(srow + i * 32) * 40 + scol]) = a4;
      *reinterpret_cast<bf16x4*>(&Bs[(srow + i * 32) * 40 + scol]) = b4;
    }
    __syncthreads();

    bf16x8 a[4], b[4];
#pragma unroll
    for (int m = 0; m < 4; ++m)
      a[m] = *reinterpret_cast<const bf16x8*>(&As[(wm + m * 16 + lr) * 40 + lk]);
#pragma unroll
    for (int n = 0; n < 4; ++n)
      b[n] = *reinterpret_cast<const bf16x8*>(&Bs[(wn + n * 16 + lr) * 40 + lk]);
#pragma unroll
    for (int m = 0; m < 4; ++m)
#pragma unroll
      for (int n = 0; n < 4; ++n)
        acc[m][n] = __builtin_amdgcn_mfma_f32_16x16x32_bf16(a[m], b[n], acc[m][n], 0, 0, 0);
  }
  __syncthreads();

  const size_t imOff = (size_t)M_DIM * OUTF;
  int fq = (lane >> 4) * 4;
#pragma unroll
  for (int m = 0; m < 4; ++m) {
    int gr = bm * 128 + wm + m * 16 + fq;
#pragma unroll
    for (int n = 0; n < 4; ++n) {
      int gc = bn * 128 + wn + n * 16 + lr;
      float* dst = (gc < OUTF) ? (out + (size_t)gr * OUTF + gc)
                               : (out + imOff + (size_t)gr * OUTF + (gc - OUTF));
#pragma unroll
      for (int j = 0; j < 4; ++j)
        dst[(size_t)j * OUTF] = acc[m][n][j];
    }
  }
}

// ---------------------------------------------------------------------------
extern "C" void kernel_launch(void* const* d_in, const int* in_sizes, int n_in,
                              void* d_out, int out_size, void* d_ws, size_t ws_size,
                              hipStream_t stream) {
  const float* xre = (const float*)d_in[0];
  const float* xim = (const float*)d_in[1];
  const float* wre = (const float*)d_in[2];
  const float* wim = (const float*)d_in[3];
  float* out = (float*)d_out;

  const size_t need = (size_t)2 * 4096 * 4096 * sizeof(bf16_t);  // 64 MiB
  if (ws_size >= need) {
    bf16_t* Abf = (bf16_t*)d_ws;
    bf16_t* Bbf = Abf + (size_t)4096 * 4096;
    hipLaunchKernelGGL(pack_ab, dim3(16384), dim3(256), 0, stream,
                       xre, xim, wre, wim, Abf, Bbf);
    hipLaunchKernelGGL(gemm256, dim3(256), dim3(512), 0, stream,
                       Abf, Bbf, out);
  } else {
    hipLaunchKernelGGL(gemm_fused, dim3(1024), dim3(256), 0, stream,
                       xre, xim, wre, wim, out);
  }
}

// Round 8
// 141.691 us; speedup vs baseline: 1.1462x; 1.0278x over previous
//
#include <hip/hip_runtime.h>

typedef __bf16 bf16_t;
typedef __bf16 bf16x8 __attribute__((ext_vector_type(8)));
typedef __bf16 bf16x4 __attribute__((ext_vector_type(4)));
typedef float f32x4 __attribute__((ext_vector_type(4)));

#define M_DIM 4096
#define N_DIM 4096   // 2 * OUT_FEATURES
#define K_DIM 4096   // 2 * IN_FEATURES
#define OUTF 2048
#define INF 2048
#define LDK 4096
#define NT 64        // K-tiles of 64

// ---------------------------------------------------------------------------
// Pack kernel: build bf16 A = [x_re | x_im]  (4096 x 4096)
//              and  bf16 B = [[w_re, -w_im]; [w_im, w_re]] (4096 x 4096)
// ---------------------------------------------------------------------------
__global__ __launch_bounds__(256) void pack_ab(
    const float* __restrict__ xre, const float* __restrict__ xim,
    const float* __restrict__ wre, const float* __restrict__ wim,
    bf16_t* __restrict__ Abf, bf16_t* __restrict__ Bbf)
{
  size_t gid = (size_t)blockIdx.x * 256 + threadIdx.x;
  size_t e8  = gid * 8;
  const size_t MAT = (size_t)4096 * 4096;
  bool isB = e8 >= MAT;
  size_t e = isB ? (e8 - MAT) : e8;
  int row = (int)(e >> 12);
  int k   = (int)(e & 4095);

  const float* src;
  float s = 1.0f;
  if (!isB) {
    src = (k < INF) ? (xre + (size_t)row * INF + k)
                    : (xim + (size_t)row * INF + (k - INF));
  } else {
    if (row < OUTF) {
      if (k < INF) { src = wre + (size_t)row * INF + k; }
      else         { src = wim + (size_t)row * INF + (k - INF); s = -1.0f; }
    } else {
      int o = row - OUTF;
      src = (k < INF) ? (wim + (size_t)o * INF + k)
                      : (wre + (size_t)o * INF + (k - INF));
    }
  }
  const float4* p = reinterpret_cast<const float4*>(src);
  float4 f0 = p[0];
  float4 f1 = p[1];
  bf16x8 v;
  v[0] = (bf16_t)(f0.x * s); v[1] = (bf16_t)(f0.y * s);
  v[2] = (bf16_t)(f0.z * s); v[3] = (bf16_t)(f0.w * s);
  v[4] = (bf16_t)(f1.x * s); v[5] = (bf16_t)(f1.y * s);
  v[6] = (bf16_t)(f1.z * s); v[7] = (bf16_t)(f1.w * s);
  bf16_t* dst = (isB ? Bbf : Abf) + e;
  *reinterpret_cast<bf16x8*>(dst) = v;
}

// ---------------------------------------------------------------------------
__device__ __forceinline__ void gld_lds16(const void* g, void* l) {
  __builtin_amdgcn_global_load_lds(
      (const __attribute__((address_space(1))) void*)g,
      (__attribute__((address_space(3))) void*)l,
      16, 0, 0);
}

// ---------------------------------------------------------------------------
// 256x256 GEMM, cross-tile read pipeline (R8).
//   8 waves = 512 thr (2M x 4N), per-wave 128x64 out, BK=64, 128 KiB dbuf.
//   Swizzle (R3-verified, conflicts==0):
//     phys_kbyte = logical_kbyte ^ ((row&3)<<4) ^ (((row>>2)&1)<<6)
//   KEY CHANGE vs R3-R7: tile t+1's Q1 reads (a0:8, b0:4) are issued at
//   tile t's P4, AFTER {vmcnt(2); BAR} (so every wave's t+1 staging loads
//   are globally drained -> no cross-thread read-before-write race) and
//   AFTER MFMA Q4 (b0's last use -> no register WAR). They drain under Q4's
//   execution + barrier, so P1's lgkm(4) is nearly free. b1/a1 issued one
//   phase early inside the tile (drain under Q1/Q2 MFMA). 2 barriers/tile:
//     P3-end (all buf-c reads complete -> t+2 staging into c safe; also
//     bounds wave skew so P4's stage can't overtake a lagging reader)
//     P4 post-vmcnt (t+1 globally resident before its reads issue).
// ---------------------------------------------------------------------------

template<int QM, int QN>
__device__ __forceinline__ void mfma_quad(f32x4 (&acc)[8][4],
                                          const bf16x8 (&aF)[4][2],
                                          const bf16x8 (&bF)[2][2]) {
  __builtin_amdgcn_s_setprio(1);
#pragma unroll
  for (int m = 0; m < 4; ++m)
#pragma unroll
    for (int n = 0; n < 2; ++n) {
      f32x4 v = acc[QM * 4 + m][QN * 2 + n];
      v = __builtin_amdgcn_mfma_f32_16x16x32_bf16(aF[m][0], bF[n][0], v, 0, 0, 0);
      v = __builtin_amdgcn_mfma_f32_16x16x32_bf16(aF[m][1], bF[n][1], v, 0, 0, 0);
      acc[QM * 4 + m][QN * 2 + n] = v;
    }
  __builtin_amdgcn_s_setprio(0);
}

__global__ __launch_bounds__(512, 2) void gemm256(
    const bf16_t* __restrict__ A, const bf16_t* __restrict__ B,
    float* __restrict__ out)
{
  // LDS: buf c at c*65536 B; within buf: A-half0|A-half1|B-half0|B-half1,
  // each half = 128 rows x 64 cols bf16 = 16384 B (row stride 128 B).
  __shared__ alignas(16) bf16_t lds[2 * 32768];
  char* Lb = (char*)lds;

  const int tid  = threadIdx.x;
  const int lane = tid & 63;
  const int wid  = tid >> 6;
  const int wm   = wid >> 2;   // 0..1  -> rows wm*128..+127  (A-half wm)
  const int wn   = wid & 3;    // 0..3  -> cols wn*64..+63
  const int lr   = lane & 15;
  const int kg   = (lane >> 4) * 16;                         // logical slot
  const int xm   = ((lr & 3) << 4) | (((lr >> 2) & 1) << 6); // row-XOR mask

  int bid = blockIdx.x;
  int swz = (bid & 7) * 32 + (bid >> 3);   // XCD-aware, 256 blocks % 8 == 0
  const int bm = swz >> 4;                  // 0..15
  const int bn = swz & 15;                  // 0..15

  // Staging source precompute: physical P = j*8192 + tid*16 within a half;
  // row = P>>7, p = P&127; logical kbyte = p ^ ((row&3)<<4) ^ ((row>>2&1)<<6)
  int rS[2], kS[2];
#pragma unroll
  for (int j = 0; j < 2; ++j) {
    int P   = j * 8192 + tid * 16;
    int row = P >> 7;
    int p   = P & 127;
    int L   = p ^ ((row & 3) << 4) ^ (((row >> 2) & 1) << 6);
    rS[j] = row;
    kS[j] = L >> 1;           // k element (0..63)
  }
  const bf16_t* As0 = A + (size_t)(bm * 256 + rS[0]) * LDK + kS[0];
  const bf16_t* As1 = A + (size_t)(bm * 256 + rS[1]) * LDK + kS[1];
  const bf16_t* Bs0 = B + (size_t)(bn * 256 + rS[0]) * LDK + kS[0];
  const bf16_t* Bs1 = B + (size_t)(bn * 256 + rS[1]) * LDK + kS[1];
  const int dst16 = tid * 16;

#define STAGE_A(t, h, c) do {                                                  \
    gld_lds16(As0 + (size_t)(h) * 128 * LDK + (t) * 64,                        \
              Lb + (c) * 65536 + (h) * 16384 + dst16);                         \
    gld_lds16(As1 + (size_t)(h) * 128 * LDK + (t) * 64,                        \
              Lb + (c) * 65536 + (h) * 16384 + 8192 + dst16);                  \
  } while (0)
#define STAGE_B(t, h, c) do {                                                  \
    gld_lds16(Bs0 + (size_t)(h) * 128 * LDK + (t) * 64,                        \
              Lb + (c) * 65536 + 32768 + (h) * 16384 + dst16);                 \
    gld_lds16(Bs1 + (size_t)(h) * 128 * LDK + (t) * 64,                        \
              Lb + (c) * 65536 + 32768 + (h) * 16384 + 8192 + dst16);          \
  } while (0)
// A frag: row-in-half = qm*64+m*16+lr (half = wm); swizzled kbyte
#define RD_A(c, qm, m, ks)                                                     \
  (*(const bf16x8*)(Lb + (c) * 65536 + wm * 16384 +                            \
                    ((qm) * 64 + (m) * 16 + lr) * 128 +                        \
                    ((((ks) * 64) | kg) ^ xm)))
// B frag: row = wn*64+qn*32+n*16+lr -> half wn>>1, row-in-half rest
#define RD_B(c, qn, n, ks)                                                     \
  (*(const bf16x8*)(Lb + (c) * 65536 + 32768 + (wn >> 1) * 16384 +             \
                    ((wn & 1) * 64 + (qn) * 32 + (n) * 16 + lr) * 128 +        \
                    ((((ks) * 64) | kg) ^ xm)))
#define BAR()   __builtin_amdgcn_s_barrier()
#define SB()    __builtin_amdgcn_sched_barrier(0)
#define ISSUE_Q1(c) do {                                                       \
    _Pragma("unroll")                                                          \
    for (int m_ = 0; m_ < 4; ++m_) {                                           \
      a0[m_][0] = RD_A(c, 0, m_, 0);                                           \
      a0[m_][1] = RD_A(c, 0, m_, 1);                                           \
    }                                                                          \
    _Pragma("unroll")                                                          \
    for (int n_ = 0; n_ < 2; ++n_) {                                           \
      b0[n_][0] = RD_B(c, 0, n_, 0);                                           \
      b0[n_][1] = RD_B(c, 0, n_, 1);                                           \
    }                                                                          \
  } while (0)

  f32x4 acc[8][4];
#pragma unroll
  for (int i = 0; i < 8; ++i)
#pragma unroll
    for (int j = 0; j < 4; ++j)
      acc[i][j] = (f32x4){0.f, 0.f, 0.f, 0.f};

  bf16x8 a0[4][2], b0[2][2];   // loop-carried: Q1 frags of the CURRENT tile

  // Prologue: tile0 fully into buf0 (8 loads); tile1's A0 into buf1 (2).
  // vmcnt(2): tile0 resident (t1-A0 in flight). Then issue Q1(t0).
  STAGE_A(0, 0, 0); STAGE_A(0, 1, 0);
  STAGE_B(0, 0, 0); STAGE_B(0, 1, 0);
  STAGE_A(1, 0, 1);
  asm volatile("s_waitcnt vmcnt(2)" ::: "memory");
  BAR();
  ISSUE_Q1(0);
  SB();

  for (int t = 0; t < NT; ++t) {
    const int c = t & 1;
    bf16x8 a1[4][2], b1[2][2];

    // ---- P1: stage t+1 A1; issue b1 (drains under Q1 MFMA).
    // lgkm(4): Q1's 12 done (issued last tile's P4, ~1 phase of cover).
    if (t + 1 < NT) STAGE_A(t + 1, 1, c ^ 1);
#pragma unroll
    for (int n = 0; n < 2; ++n) {
      b1[n][0] = RD_B(c, 1, n, 0);
      b1[n][1] = RD_B(c, 1, n, 1);
    }
    SB();
    asm volatile("s_waitcnt lgkmcnt(4)" ::: "memory");
    SB();
    mfma_quad<0, 0>(acc, a0, b0);

    // ---- P2: stage t+1 B0; issue a1 (drains under Q2). lgkm(8): b1 done.
    if (t + 1 < NT) STAGE_B(t + 1, 0, c ^ 1);
#pragma unroll
    for (int m = 0; m < 4; ++m) {
      a1[m][0] = RD_A(c, 1, m, 0);
      a1[m][1] = RD_A(c, 1, m, 1);
    }
    SB();
    asm volatile("s_waitcnt lgkmcnt(8)" ::: "memory");
    SB();
    mfma_quad<0, 1>(acc, a0, b1);

    // ---- P3: stage t+1 B1; lgkm(0): a1 done. BAR: all waves' buf-c reads
    // complete -> t+2 staging into c is safe (and bounds wave skew).
    if (t + 1 < NT) STAGE_B(t + 1, 1, c ^ 1);
    asm volatile("s_waitcnt lgkmcnt(0)" ::: "memory");
    SB();
    mfma_quad<1, 1>(acc, a1, b1);
    BAR();

    // ---- P4: stage t+2 A0 into buf c; vmcnt(2)+BAR: every wave's t+1
    // staging loads drained -> buf c^1 globally resident. MFMA Q4 (last use
    // of b0), THEN issue next tile's Q1 into a0/b0 (drains under Q4 exec).
    if (t + 2 < NT) STAGE_A(t + 2, 0, c);
    if (t + 2 < NT) {
      asm volatile("s_waitcnt vmcnt(2)" ::: "memory");
    } else if (t + 1 < NT) {
      asm volatile("s_waitcnt vmcnt(0)" ::: "memory");
    }
    BAR();
    mfma_quad<1, 0>(acc, a1, b0);
    if (t + 1 < NT) {
      SB();
      ISSUE_Q1(c ^ 1);
      SB();
    }
  }

  // Epilogue: C/D layout col=lane&15, row=(lane>>4)*4+j (verified m89/m91)
  const size_t imOff = (size_t)M_DIM * OUTF;
  const int fq = (lane >> 4) * 4;
  const bool isIm = (bn * 256) >= OUTF;          // bn>=8 -> imaginary half
  float* obase = out + (isIm ? imOff : 0);
  const int colBase = bn * 256 - (isIm ? OUTF : 0) + wn * 64;
#pragma unroll
  for (int ar = 0; ar < 8; ++ar) {
    int gr = bm * 256 + wm * 128 + ar * 16 + fq;
#pragma unroll
    for (int cc = 0; cc < 4; ++cc) {
      int gc = colBase + cc * 16 + lr;
#pragma unroll
      for (int j = 0; j < 4; ++j)
        obase[(size_t)(gr + j) * OUTF + gc] = acc[ar][cc][j];
    }
  }
#undef STAGE_A
#undef STAGE_B
#undef RD_A
#undef RD_B
#undef BAR
#undef SB
#undef ISSUE_Q1
}

// ---------------------------------------------------------------------------
// Fallback: fused fp32->bf16 conversion + GEMM (no workspace needed).
// ---------------------------------------------------------------------------
__global__ __launch_bounds__(256) void gemm_fused(
    const float* __restrict__ xre, const float* __restrict__ xim,
    const float* __restrict__ wre, const float* __restrict__ wim,
    float* __restrict__ out)
{
  __shared__ alignas(16) bf16_t As[128 * 40];
  __shared__ alignas(16) bf16_t Bs[128 * 40];

  int tid = threadIdx.x;
  int bid = blockIdx.x;
  int swz = (bid & 7) * 128 + (bid >> 3);
  int bm = swz >> 5;
  int bn = swz & 31;

  int lane = tid & 63;
  int w    = tid >> 6;
  int wm   = (w >> 1) * 64;
  int wn   = (w & 1) * 64;
  int lr   = lane & 15;
  int lk   = (lane >> 4) * 8;

  f32x4 acc[4][4];
#pragma unroll
  for (int m = 0; m < 4; ++m)
#pragma unroll
    for (int n = 0; n < 4; ++n)
      acc[m][n] = (f32x4){0.f, 0.f, 0.f, 0.f};

  int srow = tid >> 3;
  int scol = (tid & 7) * 4;

  bool nIm  = (bn * 128) >= OUTF;
  int nbase = nIm ? (bn * 128 - OUTF) : (bn * 128);

  for (int kt = 0; kt < K_DIM / 32; ++kt) {
    int k0 = kt * 32;
    bool kHi = (k0 >= INF);
    int kk = kHi ? (k0 - INF) : k0;

    const float* Asrc = (kHi ? xim : xre) + (size_t)(bm * 128) * INF + kk;
    const float* Bsrc;
    float s = 1.0f;
    if (!nIm) { if (!kHi) { Bsrc = wre; } else { Bsrc = wim; s = -1.0f; } }
    else      { Bsrc = kHi ? wre : wim; }
    Bsrc += (size_t)nbase * INF + kk;

    float4 av[4], bv[4];
#pragma unroll
    for (int i = 0; i < 4; ++i) {
      av[i] = *reinterpret_cast<const float4*>(Asrc + (size_t)(srow + i * 32) * INF + scol);
      bv[i] = *reinterpret_cast<const float4*>(Bsrc + (size_t)(srow + i * 32) * INF + scol);
    }
    __syncthreads();
#pragma unroll
    for (int i = 0; i < 4; ++i) {
      bf16x4 a4, b4;
      a4[0] = (bf16_t)av[i].x; a4[1] = (bf16_t)av[i].y;
      a4[2] = (bf16_t)av[i].z; a4[3] = (bf16_t)av[i].w;
      b4[0] = (bf16_t)(bv[i].x * s); b4[1] = (bf16_t)(bv[i].y * s);
      b4[2] = (bf16_t)(bv[i].z * s); b4[3] = (bf16_t)(bv[i].w * s);
      *reinterpret_cast<bf16x4*>(&As[(srow + i * 32) * 40 + scol]) = a4;
      *reinterpret_cast<bf16x4*>(&Bs[(srow + i * 32) * 40 + scol]) = b4;
    }
    __syncthreads();

    bf16x8 a[4], b[4];
#pragma unroll
    for (int m = 0; m < 4; ++m)
      a[m] = *reinterpret_cast<const bf16x8*>(&As[(wm + m * 16 + lr) * 40 + lk]);
#pragma unroll
    for (int n = 0; n < 4; ++n)
      b[n] = *reinterpret_cast<const bf16x8*>(&Bs[(wn + n * 16 + lr) * 40 + lk]);
#pragma unroll
    for (int m = 0; m < 4; ++m)
#pragma unroll
      for (int n = 0; n < 4; ++n)
        acc[m][n] = __builtin_amdgcn_mfma_f32_16x16x32_bf16(a[m], b[n], acc[m][n], 0, 0, 0);
  }
  __syncthreads();

  const size_t imOff = (size_t)M_DIM * OUTF;
  int fq = (lane >> 4) * 4;
#pragma unroll
  for (int m = 0; m < 4; ++m) {
    int gr = bm * 128 + wm + m * 16 + fq;
#pragma unroll
    for (int n = 0; n < 4; ++n) {
      int gc = bn * 128 + wn + n * 16 + lr;
      float* dst = (gc < OUTF) ? (out + (size_t)gr * OUTF + gc)
                               : (out + imOff + (size_t)gr * OUTF + (gc - OUTF));
#pragma unroll
      for (int j = 0; j < 4; ++j)
        dst[(size_t)j * OUTF] = acc[m][n][j];
    }
  }
}

// ---------------------------------------------------------------------------
extern "C" void kernel_launch(void* const* d_in, const int* in_sizes, int n_in,
                              void* d_out, int out_size, void* d_ws, size_t ws_size,
                              hipStream_t stream) {
  const float* xre = (const float*)d_in[0];
  const float* xim = (const float*)d_in[1];
  const float* wre = (const float*)d_in[2];
  const float* wim = (const float*)d_in[3];
  float* out = (float*)d_out;

  const size_t need = (size_t)2 * 4096 * 4096 * sizeof(bf16_t);  // 64 MiB
  if (ws_size >= need) {
    bf16_t* Abf = (bf16_t*)d_ws;
    bf16_t* Bbf = Abf + (size_t)4096 * 4096;
    hipLaunchKernelGGL(pack_ab, dim3(16384), dim3(256), 0, stream,
                       xre, xim, wre, wim, Abf, Bbf);
    hipLaunchKernelGGL(gemm256, dim3(256), dim3(512), 0, stream,
                       Abf, Bbf, out);
  } else {
    hipLaunchKernelGGL(gemm_fused, dim3(1024), dim3(256), 0, stream,
                       xre, xim, wre, wim, out);
  }
}